// Round 4
// baseline (209.470 us; speedup 1.0000x reference)
//
#include <hip/hip_runtime.h>
#include <math.h>

// CorrNet fused MFMA-f16 kernel, register-resident state (no LDS).
// M=128, K=64, T=64, N=131072, D_IN=320.
// Transposed GEMMs: D = W^T-frag * state^T-frag -> C-layout (col=sample, row=feature)
// == state layout, so residual/gate/quad phases are pure register math.
// B-fragments (state^T) synthesized via cvt_pkrtz + __shfl.

typedef _Float16 f16;
typedef _Float16 f16x8 __attribute__((ext_vector_type(8)));
typedef __fp16   fp16x2 __attribute__((ext_vector_type(2)));
typedef float    f32x4 __attribute__((ext_vector_type(4)));
typedef int      i32x4 __attribute__((ext_vector_type(4)));

#define MFMA16(a, b, c) __builtin_amdgcn_mfma_f32_16x16x32_f16(a, b, c, 0, 0, 0)

constexpr float INV_SQRT_M = 0.08838834764831845f;   // 1/sqrt(128)
constexpr float INV_SQRT_K = 0.125f;                 // 1/sqrt(64)
constexpr float INV_SQRT_3 = 0.57735026918962576f;
constexpr float TP_NORM    = 0.011048543456039806f;  // 1/sqrt(2*64*64)

// packed-weight segment offsets in f16 units (base = d_ws + 16 bytes)
#define OFF_W01 0
#define OFF_W11 24576
#define OFF_W02 28672
#define OFF_W12 53248
#define OFF_W0O 57344
#define OFF_W1O 65536
#define OFF_TP0 69632
#define OFF_TP1 73728
#define PACK_UNITS 9728   // total f16x8 units

// ---------------------------------------------------------------------------
// consts: replicate numpy trapz for C_SILU / C_RELU in fp64.
// ws[0] = 1/C_SILU, ws[1] = 1/C_RELU.
// ---------------------------------------------------------------------------
__global__ void init_consts_kernel(float* __restrict__ ws) {
    __shared__ double red[256];
    const int t = threadIdx.x;
    double acc_s = 0.0, acc_r = 0.0;
    for (int i = t; i <= 20000; i += 256) {
        const double z = -8.0 + (16.0 * (double)i) / 20000.0;
        const double pdf = exp(-0.5 * z * z) / 2.5066282746310002;
        const double sil = z / (1.0 + exp(-z));
        const double wgt = (i == 0 || i == 20000) ? 0.5 : 1.0;
        acc_s += wgt * sil * sil * pdf;
        if (z > 0.0) acc_r += wgt * z * z * pdf;
    }
    red[t] = acc_s;
    __syncthreads();
    for (int o = 128; o > 0; o >>= 1) { if (t < o) red[t] += red[t + o]; __syncthreads(); }
    const double tot_s = red[0];
    __syncthreads();
    red[t] = acc_r;
    __syncthreads();
    for (int o = 128; o > 0; o >>= 1) { if (t < o) red[t] += red[t + o]; __syncthreads(); }
    if (t == 0) {
        const double dz = 16.0 / 20000.0;
        ws[0] = (float)(1.0 / sqrt(tot_s * dz));
        ws[1] = (float)(1.0 / sqrt(red[0] * dz));
    }
}

// ---------------------------------------------------------------------------
// Pack weights fp32 -> f16 fragments (A-frag of W^T == B-frag of W; unchanged).
// Fragment (kstep, nj): lane l, elem e holds W[kstep*32 + (l>>4)*8 + e][nj*16 + (l&15)]
// stored at dst[base + ((kstep*NT + nj)*64 + l)*8 + e].
// ---------------------------------------------------------------------------
__global__ void pack_weights(const float* __restrict__ w01, const float* __restrict__ w11,
                             const float* __restrict__ w02, const float* __restrict__ w12,
                             const float* __restrict__ w0o, const float* __restrict__ w1o,
                             const float* __restrict__ tp0, const float* __restrict__ tp1,
                             f16* __restrict__ dst) {
    int u = blockIdx.x * 256 + threadIdx.x;
    if (u >= PACK_UNITS) return;
    const float* src; int NC, base, lu = u;
    if      (lu < 3072) {            src = w01; NC = 192; base = OFF_W01; }
    else if (lu < 3584) { lu -= 3072; src = w11; NC = 64;  base = OFF_W11; }
    else if (lu < 6656) { lu -= 3584; src = w02; NC = 192; base = OFF_W02; }
    else if (lu < 7168) { lu -= 6656; src = w12; NC = 64;  base = OFF_W12; }
    else if (lu < 8192) { lu -= 7168; src = w0o; NC = 64;  base = OFF_W0O; }
    else if (lu < 8704) { lu -= 8192; src = w1o; NC = 64;  base = OFF_W1O; }
    else if (lu < 9216) { lu -= 8704; src = tp0; NC = 64;  base = OFF_TP0; }
    else                { lu -= 9216; src = tp1; NC = 64;  base = OFF_TP1; }
    const int lane = lu & 63;
    const int frag = lu >> 6;          // kstep*NT + nj
    const int NT = NC >> 4;
    const int kstep = frag / NT, nj = frag - kstep * NT;
    const int row0 = kstep * 32 + (lane >> 4) * 8;
    const int col  = nj * 16 + (lane & 15);
    f16 tmp[8];
    #pragma unroll
    for (int e = 0; e < 8; ++e) tmp[e] = (f16)src[(size_t)(row0 + e) * NC + col];
    *(f16x8*)&dst[(size_t)(base) + (size_t)lu * 8] = *(f16x8*)tmp;
}

// ---------------------------------------------------------------------------
__device__ __forceinline__ int pk2i(float a, float b) {
    union { fp16x2 h; int i; } u;
    u.h = __builtin_amdgcn_cvt_pkrtz(a, b);
    return u.i;
}

// Synthesize a B-fragment (state^T, 32 k x 16 samples) from two C-layout
// state tiles t0 (features f_base..+15) and t1 (features f_base+16..+31).
// Target lane (g,c), dword d holds features f_base + 8g + 2d, +1 (as f16x2),
// sourced from lane (g&1)*32 + (d>>1)*16 + c, pk-pair (d&1), tile (g>>1).
__device__ __forceinline__ f16x8 synthB(f32x4 t0, f32x4 t1, int lane_lo, bool ghi) {
    const int p00 = pk2i(t0[0], t0[1]);
    const int p01 = pk2i(t0[2], t0[3]);
    const int p10 = pk2i(t1[0], t1[1]);
    const int p11 = pk2i(t1[2], t1[3]);
    union { i32x4 i; f16x8 v; } u;
    #pragma unroll
    for (int d = 0; d < 4; ++d) {
        const int src = lane_lo + ((d >> 1) << 4);
        const int lo = __shfl((d & 1) ? p01 : p00, src, 64);
        const int hi = __shfl((d & 1) ? p11 : p10, src, 64);
        u.i[d] = ghi ? hi : lo;
    }
    return u.v;
}

// ---------------------------------------------------------------------------
// One residual block, all state in registers.
// xs[8]: feature tiles of xs (16 each); xv[i][4]: feature tiles of xv_i.
// ---------------------------------------------------------------------------
__device__ __forceinline__ void resblock(
    f32x4 xs[8], f32x4 xv[3][4],
    const f16* __restrict__ w0p, const f16* __restrict__ w1p,
    const float* __restrict__ b0,
    float invCS, float invCR, int l, int g, int lane_lo, bool ghi)
{
    // snapshot state as B-fragments
    f16x8 xsB[4];
    #pragma unroll
    for (int ks = 0; ks < 4; ++ks)
        xsB[ks] = synthB(xs[2 * ks], xs[2 * ks + 1], lane_lo, ghi);
    f16x8 xvB[3][2];
    #pragma unroll
    for (int i = 0; i < 3; ++i)
        #pragma unroll
        for (int ks = 0; ks < 2; ++ks)
            xvB[i][ks] = synthB(xv[i][2 * ks], xv[i][2 * ks + 1], lane_lo, ghi);

    f32x4 gate[4];
    // ys^T = W0^T @ xs^T : 12 row-tiles of 16 output features
    #pragma unroll
    for (int nj = 0; nj < 12; ++nj) {
        f32x4 acc = {0.f, 0.f, 0.f, 0.f};
        #pragma unroll
        for (int ks = 0; ks < 4; ++ks) {
            const f16x8 a = *(const f16x8*)&w0p[(size_t)((ks * 12 + nj) * 64 + l) * 8];
            acc = MFMA16(a, xsB[ks], acc);
        }
        const f32x4 bias = *(const f32x4*)(b0 + nj * 16 + g * 4);
        if (nj < 8) {
            #pragma unroll
            for (int r = 0; r < 4; ++r) {
                const float ys = acc[r] * INV_SQRT_M + bias[r];
                xs[nj][r] += ys / (1.0f + __expf(-ys)) * invCS;
            }
        } else {
            #pragma unroll
            for (int r = 0; r < 4; ++r) {
                const float ys = acc[r] * INV_SQRT_M + bias[r];
                gate[nj - 8][r] = fmaxf(ys, 0.f) * invCR;
            }
        }
    }
    // yv^T per i, gated residual update
    #pragma unroll
    for (int i = 0; i < 3; ++i)
        #pragma unroll
        for (int nj = 0; nj < 4; ++nj) {
            f32x4 acc = {0.f, 0.f, 0.f, 0.f};
            #pragma unroll
            for (int ks = 0; ks < 2; ++ks) {
                const f16x8 a = *(const f16x8*)&w1p[(size_t)((ks * 4 + nj) * 64 + l) * 8];
                acc = MFMA16(a, xvB[i][ks], acc);
            }
            #pragma unroll
            for (int r = 0; r < 4; ++r)
                xv[i][nj][r] += acc[r] * INV_SQRT_K * gate[nj][r];
        }
}

// ---------------------------------------------------------------------------
__global__ __launch_bounds__(256, 2)
void corrnet_reg(const float* __restrict__ x, const float* __restrict__ shift,
                 const float* __restrict__ oscale,
                 const float* __restrict__ b01, const float* __restrict__ b02,
                 const float* __restrict__ b0o,
                 const f16* __restrict__ wp, const float* __restrict__ consts,
                 float* __restrict__ out)
{
    const int t = threadIdx.x;
    const int l = t & 63;
    const int w = __builtin_amdgcn_readfirstlane(t >> 6);
    const int g = l >> 4;
    const int c = l & 15;
    const size_t n0 = (size_t)blockIdx.x * 64 + (size_t)w * 16;
    const bool ghi = g >= 2;
    const int lane_lo = ((g & 1) << 5) + c;

    const float invCS = consts[0], invCR = consts[1];
    const float inv_os = 1.0f / oscale[0];

    // ---- load x row -> C-layout register state, subtract shift ----
    f32x4 xs[8];
    f32x4 xv[3][4];
    const float* xrow = x + (n0 + c) * 320;
    #pragma unroll
    for (int tau = 0; tau < 8; ++tau) {
        const int col = tau * 16 + g * 4;
        const f32x4 v = *(const f32x4*)(xrow + col);
        const f32x4 s = *(const f32x4*)(shift + col);
        xs[tau] = v - s;
    }
    #pragma unroll
    for (int tau = 0; tau < 4; ++tau) {
        const int col = 128 + 3 * (tau * 16 + g * 4);
        const f32x4 a0 = *(const f32x4*)(xrow + col);
        const f32x4 a1 = *(const f32x4*)(xrow + col + 4);
        const f32x4 a2 = *(const f32x4*)(xrow + col + 8);
        const f32x4 s0 = *(const f32x4*)(shift + col);
        const f32x4 s1 = *(const f32x4*)(shift + col + 4);
        const f32x4 s2 = *(const f32x4*)(shift + col + 8);
        float arr[12];
        #pragma unroll
        for (int e = 0; e < 4; ++e) {
            arr[e]     = a0[e] - s0[e];
            arr[4 + e] = a1[e] - s1[e];
            arr[8 + e] = a2[e] - s2[e];
        }
        #pragma unroll
        for (int r = 0; r < 4; ++r)
            #pragma unroll
            for (int i = 0; i < 3; ++i)
                xv[i][tau][r] = arr[3 * r + i];
    }

    resblock(xs, xv, wp + OFF_W01, wp + OFF_W11, b01, invCS, invCR, l, g, lane_lo, ghi);
    resblock(xs, xv, wp + OFF_W02, wp + OFF_W12, b02, invCS, invCR, l, g, lane_lo, ghi);

    // ---- output head ----
    f16x8 xsB[4];
    #pragma unroll
    for (int ks = 0; ks < 4; ++ks)
        xsB[ks] = synthB(xs[2 * ks], xs[2 * ks + 1], lane_lo, ghi);
    f16x8 xvB[3][2];
    #pragma unroll
    for (int i = 0; i < 3; ++i)
        #pragma unroll
        for (int ks = 0; ks < 2; ++ks)
            xvB[i][ks] = synthB(xv[i][2 * ks], xv[i][2 * ks + 1], lane_lo, ghi);

    f32x4 zs[4];
    #pragma unroll
    for (int nj = 0; nj < 4; ++nj) {
        f32x4 acc = {0.f, 0.f, 0.f, 0.f};
        #pragma unroll
        for (int ks = 0; ks < 4; ++ks) {
            const f16x8 a = *(const f16x8*)&wp[OFF_W0O + (size_t)((ks * 4 + nj) * 64 + l) * 8];
            acc = MFMA16(a, xsB[ks], acc);
        }
        const f32x4 bias = *(const f32x4*)(b0o + nj * 16 + g * 4);
        #pragma unroll
        for (int r = 0; r < 4; ++r)
            zs[nj][r] = acc[r] * INV_SQRT_M + bias[r];
    }
    f32x4 zv[3][4];
    #pragma unroll
    for (int i = 0; i < 3; ++i)
        #pragma unroll
        for (int nj = 0; nj < 4; ++nj) {
            f32x4 acc = {0.f, 0.f, 0.f, 0.f};
            #pragma unroll
            for (int ks = 0; ks < 2; ++ks) {
                const f16x8 a = *(const f16x8*)&wp[OFF_W1O + (size_t)((ks * 4 + nj) * 64 + l) * 8];
                acc = MFMA16(a, xvB[i][ks], acc);
            }
            #pragma unroll
            for (int r = 0; r < 4; ++r)
                zv[i][nj][r] = acc[r] * INV_SQRT_K;
        }

    // ---- quadratic forms ----
    f16x8 zsB[2];
    #pragma unroll
    for (int ks = 0; ks < 2; ++ks)
        zsB[ks] = synthB(zs[2 * ks], zs[2 * ks + 1], lane_lo, ghi);
    f16x8 zvB[3][2];
    #pragma unroll
    for (int i = 0; i < 3; ++i)
        #pragma unroll
        for (int ks = 0; ks < 2; ++ks)
            zvB[i][ks] = synthB(zv[i][2 * ks], zv[i][2 * ks + 1], lane_lo, ghi);

    float part = 0.f;
    #pragma unroll
    for (int nj = 0; nj < 4; ++nj) {
        f32x4 acc = {0.f, 0.f, 0.f, 0.f};
        #pragma unroll
        for (int ks = 0; ks < 2; ++ks) {
            const f16x8 a = *(const f16x8*)&wp[OFF_TP0 + (size_t)((ks * 4 + nj) * 64 + l) * 8];
            acc = MFMA16(a, zsB[ks], acc);
        }
        #pragma unroll
        for (int r = 0; r < 4; ++r)
            part += acc[r] * zs[nj][r];
    }
    float part1 = 0.f;
    #pragma unroll
    for (int i = 0; i < 3; ++i)
        #pragma unroll
        for (int nj = 0; nj < 4; ++nj) {
            f32x4 acc = {0.f, 0.f, 0.f, 0.f};
            #pragma unroll
            for (int ks = 0; ks < 2; ++ks) {
                const f16x8 a = *(const f16x8*)&wp[OFF_TP1 + (size_t)((ks * 4 + nj) * 64 + l) * 8];
                acc = MFMA16(a, zvB[i][ks], acc);
            }
            #pragma unroll
            for (int r = 0; r < 4; ++r)
                part1 += acc[r] * zv[i][nj][r];
        }
    part += part1 * INV_SQRT_3;

    // reduce over the 4 g-groups (features) -> per-sample total
    part += __shfl_xor(part, 16, 64);
    part += __shfl_xor(part, 32, 64);

    if (l < 16)
        out[n0 + l] = part * TP_NORM * inv_os;
}

// ---------------------------------------------------------------------------
extern "C" void kernel_launch(void* const* d_in, const int* in_sizes, int n_in,
                              void* d_out, int out_size, void* d_ws, size_t ws_size,
                              hipStream_t stream) {
    const float* x      = (const float*)d_in[0];
    const float* shift  = (const float*)d_in[1];
    const float* oscale = (const float*)d_in[2];
    const float* w01    = (const float*)d_in[3];
    const float* b01    = (const float*)d_in[4];
    const float* w11    = (const float*)d_in[5];
    const float* w02    = (const float*)d_in[6];
    const float* b02    = (const float*)d_in[7];
    const float* w12    = (const float*)d_in[8];
    const float* w0o    = (const float*)d_in[9];
    const float* b0o    = (const float*)d_in[10];
    const float* w1o    = (const float*)d_in[11];
    const float* wtp0   = (const float*)d_in[12];
    const float* wtp1   = (const float*)d_in[13];
    float* out    = (float*)d_out;
    float* consts = (float*)d_ws;
    f16*   wp     = (f16*)((char*)d_ws + 16);

    init_consts_kernel<<<1, 256, 0, stream>>>(consts);
    pack_weights<<<(PACK_UNITS + 255) / 256, 256, 0, stream>>>(
        w01, w11, w02, w12, w0o, w1o, wtp0, wtp1, wp);

    const int nblocks = 131072 / 64;  // 2048
    corrnet_reg<<<nblocks, 256, 0, stream>>>(
        x, shift, oscale, b01, b02, b0o, wp, consts, out);
}

// Round 5
// 103.001 us; speedup vs baseline: 2.0337x; 2.0337x over previous
//
#include <hip/hip_runtime.h>
#include <math.h>

// CorrNet fused MFMA-f16 kernel, register-resident state, ZERO cross-lane ops.
// M=128, K=64, T=64, N=131072, D_IN=320.
// Transposed GEMMs: D = W^T-frag * state^T-frag -> C-layout (col=sample).
// Feature-permutation trick: state features are stored in permuted order
// phi(k=8g+2d+p) so that in-lane cvt_pkrtz of two D-tiles IS a valid
// B-fragment; phi is baked into the weight-row packing. No shfl, no LDS.

typedef _Float16 f16;
typedef _Float16 f16x8 __attribute__((ext_vector_type(8)));
typedef __fp16   fp16x2 __attribute__((ext_vector_type(2)));
typedef float    f32x4 __attribute__((ext_vector_type(4)));
typedef int      i32x4 __attribute__((ext_vector_type(4)));

#define MFMA16(a, b, c) __builtin_amdgcn_mfma_f32_16x16x32_f16(a, b, c, 0, 0, 0)

constexpr float INV_SQRT_M = 0.08838834764831845f;   // 1/sqrt(128)
constexpr float INV_SQRT_K = 0.125f;                 // 1/sqrt(64)
constexpr float INV_SQRT_3 = 0.57735026918962576f;
constexpr float TP_NORM    = 0.011048543456039806f;  // 1/sqrt(2*64*64)

// packed-weight segment offsets in f16 units (base = d_ws + 16 bytes)
#define OFF_W01 0
#define OFF_W11 24576
#define OFF_W02 28672
#define OFF_W12 53248
#define OFF_W0O 57344
#define OFF_W1O 65536
#define OFF_TP0 69632
#define OFF_TP1 73728
#define PACK_UNITS 9728   // total f16x8 units

// ---------------------------------------------------------------------------
// consts: replicate numpy trapz for C_SILU / C_RELU in fp64.
// ws[0] = 1/C_SILU, ws[1] = 1/C_RELU.
// ---------------------------------------------------------------------------
__global__ void init_consts_kernel(float* __restrict__ ws) {
    __shared__ double red[256];
    const int t = threadIdx.x;
    double acc_s = 0.0, acc_r = 0.0;
    for (int i = t; i <= 20000; i += 256) {
        const double z = -8.0 + (16.0 * (double)i) / 20000.0;
        const double pdf = exp(-0.5 * z * z) / 2.5066282746310002;
        const double sil = z / (1.0 + exp(-z));
        const double wgt = (i == 0 || i == 20000) ? 0.5 : 1.0;
        acc_s += wgt * sil * sil * pdf;
        if (z > 0.0) acc_r += wgt * z * z * pdf;
    }
    red[t] = acc_s;
    __syncthreads();
    for (int o = 128; o > 0; o >>= 1) { if (t < o) red[t] += red[t + o]; __syncthreads(); }
    const double tot_s = red[0];
    __syncthreads();
    red[t] = acc_r;
    __syncthreads();
    for (int o = 128; o > 0; o >>= 1) { if (t < o) red[t] += red[t + o]; __syncthreads(); }
    if (t == 0) {
        const double dz = 16.0 / 20000.0;
        ws[0] = (float)(1.0 / sqrt(tot_s * dz));
        ws[1] = (float)(1.0 / sqrt(red[0] * dz));
    }
}

// ---------------------------------------------------------------------------
// Pack weights fp32 -> f16 A-fragments of W^T, with phi-permuted k-rows.
// Fragment (kstep, nj), lane l, elem e holds
//   W[kstep*32 + 16*(e>>2) + 4*(l>>4) + (e&3)][nj*16 + (l&15)]
// stored at dst[base + ((kstep*NT + nj)*64 + l)*8 + e].
// phi matches the in-lane pk-packing of two D-tiles into one B-fragment.
// ---------------------------------------------------------------------------
__global__ void pack_weights(const float* __restrict__ w01, const float* __restrict__ w11,
                             const float* __restrict__ w02, const float* __restrict__ w12,
                             const float* __restrict__ w0o, const float* __restrict__ w1o,
                             const float* __restrict__ tp0, const float* __restrict__ tp1,
                             f16* __restrict__ dst) {
    int u = blockIdx.x * 256 + threadIdx.x;
    if (u >= PACK_UNITS) return;
    const float* src; int NC, base, lu = u;
    if      (lu < 3072) {            src = w01; NC = 192; base = OFF_W01; }
    else if (lu < 3584) { lu -= 3072; src = w11; NC = 64;  base = OFF_W11; }
    else if (lu < 6656) { lu -= 3584; src = w02; NC = 192; base = OFF_W02; }
    else if (lu < 7168) { lu -= 6656; src = w12; NC = 64;  base = OFF_W12; }
    else if (lu < 8192) { lu -= 7168; src = w0o; NC = 64;  base = OFF_W0O; }
    else if (lu < 8704) { lu -= 8192; src = w1o; NC = 64;  base = OFF_W1O; }
    else if (lu < 9216) { lu -= 8704; src = tp0; NC = 64;  base = OFF_TP0; }
    else                { lu -= 9216; src = tp1; NC = 64;  base = OFF_TP1; }
    const int lane = lu & 63;
    const int frag = lu >> 6;          // kstep*NT + nj
    const int NT = NC >> 4;
    const int kstep = frag / NT, nj = frag - kstep * NT;
    const int gl  = lane >> 4;
    const int col = nj * 16 + (lane & 15);
    f16 tmp[8];
    #pragma unroll
    for (int e = 0; e < 8; ++e) {
        const int row = kstep * 32 + ((e >> 2) << 4) + (gl << 2) + (e & 3);  // phi
        tmp[e] = (f16)src[(size_t)row * NC + col];
    }
    *(f16x8*)&dst[(size_t)(base) + (size_t)lu * 8] = *(f16x8*)tmp;
}

// ---------------------------------------------------------------------------
__device__ __forceinline__ int pk2i(float a, float b) {
    union { fp16x2 h; int i; } u;
    u.h = __builtin_amdgcn_cvt_pkrtz(a, b);
    return u.i;
}

// B-fragment from two D-layout f32 tiles: pure in-lane packing (phi-relabeled).
__device__ __forceinline__ f16x8 packB(f32x4 t0, f32x4 t1) {
    union { i32x4 i; f16x8 v; } u;
    u.i[0] = pk2i(t0[0], t0[1]);
    u.i[1] = pk2i(t0[2], t0[3]);
    u.i[2] = pk2i(t1[0], t1[1]);
    u.i[3] = pk2i(t1[2], t1[3]);
    return u.v;
}

// ---------------------------------------------------------------------------
// One residual block, all state in registers.
// xs[8]: D-layout feature tiles of xs; xv[i][4]: tiles of xv_i.
// ---------------------------------------------------------------------------
__device__ __forceinline__ void resblock(
    f32x4 xs[8], f32x4 xv[3][4],
    const f16* __restrict__ w0p, const f16* __restrict__ w1p,
    const float* __restrict__ b0,
    float invCS, float invCR, int l, int g)
{
    // snapshot state as B-fragments (in-lane)
    f16x8 xsB[4];
    #pragma unroll
    for (int ks = 0; ks < 4; ++ks)
        xsB[ks] = packB(xs[2 * ks], xs[2 * ks + 1]);
    f16x8 xvB[3][2];
    #pragma unroll
    for (int i = 0; i < 3; ++i)
        #pragma unroll
        for (int ks = 0; ks < 2; ++ks)
            xvB[i][ks] = packB(xv[i][2 * ks], xv[i][2 * ks + 1]);

    f32x4 gate[4];
    // ys^T = W0^T @ xs^T : 12 row-tiles of 16 output features
    #pragma unroll
    for (int nj = 0; nj < 12; ++nj) {
        f32x4 acc = {0.f, 0.f, 0.f, 0.f};
        #pragma unroll
        for (int ks = 0; ks < 4; ++ks) {
            const f16x8 a = *(const f16x8*)&w0p[(size_t)((ks * 12 + nj) * 64 + l) * 8];
            acc = MFMA16(a, xsB[ks], acc);
        }
        const f32x4 bias = *(const f32x4*)(b0 + nj * 16 + g * 4);
        if (nj < 8) {
            #pragma unroll
            for (int r = 0; r < 4; ++r) {
                const float ys = acc[r] * INV_SQRT_M + bias[r];
                xs[nj][r] += ys / (1.0f + __expf(-ys)) * invCS;
            }
        } else {
            #pragma unroll
            for (int r = 0; r < 4; ++r) {
                const float ys = acc[r] * INV_SQRT_M + bias[r];
                gate[nj - 8][r] = fmaxf(ys, 0.f) * invCR;
            }
        }
    }
    // yv^T per i, gated residual update
    #pragma unroll
    for (int i = 0; i < 3; ++i)
        #pragma unroll
        for (int nj = 0; nj < 4; ++nj) {
            f32x4 acc = {0.f, 0.f, 0.f, 0.f};
            #pragma unroll
            for (int ks = 0; ks < 2; ++ks) {
                const f16x8 a = *(const f16x8*)&w1p[(size_t)((ks * 4 + nj) * 64 + l) * 8];
                acc = MFMA16(a, xvB[i][ks], acc);
            }
            #pragma unroll
            for (int r = 0; r < 4; ++r)
                xv[i][nj][r] += acc[r] * INV_SQRT_K * gate[nj][r];
        }
}

// ---------------------------------------------------------------------------
__global__ __launch_bounds__(256, 2)
void corrnet_reg(const float* __restrict__ x, const float* __restrict__ shift,
                 const float* __restrict__ oscale,
                 const float* __restrict__ b01, const float* __restrict__ b02,
                 const float* __restrict__ b0o,
                 const f16* __restrict__ wp, const float* __restrict__ consts,
                 float* __restrict__ out)
{
    const int t = threadIdx.x;
    const int l = t & 63;
    const int w = __builtin_amdgcn_readfirstlane(t >> 6);
    const int g = l >> 4;
    const int c = l & 15;
    const size_t n0 = (size_t)blockIdx.x * 64 + (size_t)w * 16;

    const float invCS = consts[0], invCR = consts[1];
    const float inv_os = 1.0f / oscale[0];

    // ---- load x row -> D-layout register state, subtract shift ----
    f32x4 xs[8];
    f32x4 xv[3][4];
    const float* xrow = x + (n0 + c) * 320;
    #pragma unroll
    for (int tau = 0; tau < 8; ++tau) {
        const int col = tau * 16 + g * 4;
        const f32x4 v = *(const f32x4*)(xrow + col);
        const f32x4 s = *(const f32x4*)(shift + col);
        xs[tau] = v - s;
    }
    #pragma unroll
    for (int tau = 0; tau < 4; ++tau) {
        const int col = 128 + 3 * (tau * 16 + g * 4);
        const f32x4 a0 = *(const f32x4*)(xrow + col);
        const f32x4 a1 = *(const f32x4*)(xrow + col + 4);
        const f32x4 a2 = *(const f32x4*)(xrow + col + 8);
        const f32x4 s0 = *(const f32x4*)(shift + col);
        const f32x4 s1 = *(const f32x4*)(shift + col + 4);
        const f32x4 s2 = *(const f32x4*)(shift + col + 8);
        float arr[12];
        #pragma unroll
        for (int e = 0; e < 4; ++e) {
            arr[e]     = a0[e] - s0[e];
            arr[4 + e] = a1[e] - s1[e];
            arr[8 + e] = a2[e] - s2[e];
        }
        #pragma unroll
        for (int r = 0; r < 4; ++r)
            #pragma unroll
            for (int i = 0; i < 3; ++i)
                xv[i][tau][r] = arr[3 * r + i];
    }

    resblock(xs, xv, wp + OFF_W01, wp + OFF_W11, b01, invCS, invCR, l, g);
    resblock(xs, xv, wp + OFF_W02, wp + OFF_W12, b02, invCS, invCR, l, g);

    // ---- output head ----
    f16x8 xsB[4];
    #pragma unroll
    for (int ks = 0; ks < 4; ++ks)
        xsB[ks] = packB(xs[2 * ks], xs[2 * ks + 1]);
    f16x8 xvB[3][2];
    #pragma unroll
    for (int i = 0; i < 3; ++i)
        #pragma unroll
        for (int ks = 0; ks < 2; ++ks)
            xvB[i][ks] = packB(xv[i][2 * ks], xv[i][2 * ks + 1]);

    f32x4 zs[4];
    #pragma unroll
    for (int nj = 0; nj < 4; ++nj) {
        f32x4 acc = {0.f, 0.f, 0.f, 0.f};
        #pragma unroll
        for (int ks = 0; ks < 4; ++ks) {
            const f16x8 a = *(const f16x8*)&wp[OFF_W0O + (size_t)((ks * 4 + nj) * 64 + l) * 8];
            acc = MFMA16(a, xsB[ks], acc);
        }
        const f32x4 bias = *(const f32x4*)(b0o + nj * 16 + g * 4);
        #pragma unroll
        for (int r = 0; r < 4; ++r)
            zs[nj][r] = acc[r] * INV_SQRT_M + bias[r];
    }
    f32x4 zv[3][4];
    #pragma unroll
    for (int i = 0; i < 3; ++i)
        #pragma unroll
        for (int nj = 0; nj < 4; ++nj) {
            f32x4 acc = {0.f, 0.f, 0.f, 0.f};
            #pragma unroll
            for (int ks = 0; ks < 2; ++ks) {
                const f16x8 a = *(const f16x8*)&wp[OFF_W1O + (size_t)((ks * 4 + nj) * 64 + l) * 8];
                acc = MFMA16(a, xvB[i][ks], acc);
            }
            #pragma unroll
            for (int r = 0; r < 4; ++r)
                zv[i][nj][r] = acc[r] * INV_SQRT_K;
        }

    // ---- quadratic forms ----
    f16x8 zsB[2];
    #pragma unroll
    for (int ks = 0; ks < 2; ++ks)
        zsB[ks] = packB(zs[2 * ks], zs[2 * ks + 1]);
    f16x8 zvB[3][2];
    #pragma unroll
    for (int i = 0; i < 3; ++i)
        #pragma unroll
        for (int ks = 0; ks < 2; ++ks)
            zvB[i][ks] = packB(zv[i][2 * ks], zv[i][2 * ks + 1]);

    float part = 0.f;
    #pragma unroll
    for (int nj = 0; nj < 4; ++nj) {
        f32x4 acc = {0.f, 0.f, 0.f, 0.f};
        #pragma unroll
        for (int ks = 0; ks < 2; ++ks) {
            const f16x8 a = *(const f16x8*)&wp[OFF_TP0 + (size_t)((ks * 4 + nj) * 64 + l) * 8];
            acc = MFMA16(a, zsB[ks], acc);
        }
        #pragma unroll
        for (int r = 0; r < 4; ++r)
            part += acc[r] * zs[nj][r];
    }
    float part1 = 0.f;
    #pragma unroll
    for (int i = 0; i < 3; ++i)
        #pragma unroll
        for (int nj = 0; nj < 4; ++nj) {
            f32x4 acc = {0.f, 0.f, 0.f, 0.f};
            #pragma unroll
            for (int ks = 0; ks < 2; ++ks) {
                const f16x8 a = *(const f16x8*)&wp[OFF_TP1 + (size_t)((ks * 4 + nj) * 64 + l) * 8];
                acc = MFMA16(a, zvB[i][ks], acc);
            }
            #pragma unroll
            for (int r = 0; r < 4; ++r)
                part1 += acc[r] * zv[i][nj][r];
        }
    part += part1 * INV_SQRT_3;

    // reduce over the 4 g-groups (features) -> per-sample total
    part += __shfl_xor(part, 16, 64);
    part += __shfl_xor(part, 32, 64);

    if (l < 16)
        out[n0 + l] = part * TP_NORM * inv_os;
}

// ---------------------------------------------------------------------------
extern "C" void kernel_launch(void* const* d_in, const int* in_sizes, int n_in,
                              void* d_out, int out_size, void* d_ws, size_t ws_size,
                              hipStream_t stream) {
    const float* x      = (const float*)d_in[0];
    const float* shift  = (const float*)d_in[1];
    const float* oscale = (const float*)d_in[2];
    const float* w01    = (const float*)d_in[3];
    const float* b01    = (const float*)d_in[4];
    const float* w11    = (const float*)d_in[5];
    const float* w02    = (const float*)d_in[6];
    const float* b02    = (const float*)d_in[7];
    const float* w12    = (const float*)d_in[8];
    const float* w0o    = (const float*)d_in[9];
    const float* b0o    = (const float*)d_in[10];
    const float* w1o    = (const float*)d_in[11];
    const float* wtp0   = (const float*)d_in[12];
    const float* wtp1   = (const float*)d_in[13];
    float* out    = (float*)d_out;
    float* consts = (float*)d_ws;
    f16*   wp     = (f16*)((char*)d_ws + 16);

    init_consts_kernel<<<1, 256, 0, stream>>>(consts);
    pack_weights<<<(PACK_UNITS + 255) / 256, 256, 0, stream>>>(
        w01, w11, w02, w12, w0o, w1o, wtp0, wtp1, wp);

    const int nblocks = 131072 / 64;  // 2048
    corrnet_reg<<<nblocks, 256, 0, stream>>>(
        x, shift, oscale, b01, b02, b0o, wp, consts, out);
}

// Round 6
// 97.017 us; speedup vs baseline: 2.1591x; 1.0617x over previous
//
#include <hip/hip_runtime.h>
#include <math.h>

// CorrNet fused MFMA-f16 kernel, v3: 32 samples/wave, f16-packed register state.
// M=128, K=64, T=64, N=131072, D_IN=320.
// Transposed GEMMs: D = W^T-frag * state^T-frag, C-layout col=sample.
// State is stored AS the B-fragment (f16x8 per 32-feature tile-pair), with
// phi-permuted feature order baked into the weight packing, so residual
// updates are in-lane v_pk_add_f16 of cvt_pkrtz pairs. Two sample-halves per
// wave share every weight A-fragment load (2 MFMAs per load).

typedef _Float16 f16;
typedef _Float16 f16x8 __attribute__((ext_vector_type(8)));
typedef __fp16   fp16x2 __attribute__((ext_vector_type(2)));
typedef float    f32x4 __attribute__((ext_vector_type(4)));
typedef int      i32x4 __attribute__((ext_vector_type(4)));

#define MFMA16(a, b, c) __builtin_amdgcn_mfma_f32_16x16x32_f16(a, b, c, 0, 0, 0)

constexpr float INV_SQRT_M = 0.08838834764831845f;   // 1/sqrt(128)
constexpr float INV_SQRT_K = 0.125f;                 // 1/sqrt(64)
constexpr float INV_SQRT_3 = 0.57735026918962576f;
constexpr float TP_NORM    = 0.011048543456039806f;  // 1/sqrt(2*64*64)

// packed-weight segment offsets in f16 units (base = d_ws + 16 bytes)
#define OFF_W01 0
#define OFF_W11 24576
#define OFF_W02 28672
#define OFF_W12 53248
#define OFF_W0O 57344
#define OFF_W1O 65536
#define OFF_TP0 69632
#define OFF_TP1 73728
#define PACK_UNITS 9728   // total f16x8 units

// ---------------------------------------------------------------------------
// consts: replicate numpy trapz for C_SILU / C_RELU in fp64.
// ws[0] = 1/C_SILU, ws[1] = 1/C_RELU.
// ---------------------------------------------------------------------------
__global__ void init_consts_kernel(float* __restrict__ ws) {
    __shared__ double red[256];
    const int t = threadIdx.x;
    double acc_s = 0.0, acc_r = 0.0;
    for (int i = t; i <= 20000; i += 256) {
        const double z = -8.0 + (16.0 * (double)i) / 20000.0;
        const double pdf = exp(-0.5 * z * z) / 2.5066282746310002;
        const double sil = z / (1.0 + exp(-z));
        const double wgt = (i == 0 || i == 20000) ? 0.5 : 1.0;
        acc_s += wgt * sil * sil * pdf;
        if (z > 0.0) acc_r += wgt * z * z * pdf;
    }
    red[t] = acc_s;
    __syncthreads();
    for (int o = 128; o > 0; o >>= 1) { if (t < o) red[t] += red[t + o]; __syncthreads(); }
    const double tot_s = red[0];
    __syncthreads();
    red[t] = acc_r;
    __syncthreads();
    for (int o = 128; o > 0; o >>= 1) { if (t < o) red[t] += red[t + o]; __syncthreads(); }
    if (t == 0) {
        const double dz = 16.0 / 20000.0;
        ws[0] = (float)(1.0 / sqrt(tot_s * dz));
        ws[1] = (float)(1.0 / sqrt(red[0] * dz));
    }
}

// ---------------------------------------------------------------------------
// Pack weights fp32 -> f16 A-fragments of W^T, with phi-permuted k-rows.
// Fragment (kstep, nj), lane l, elem e holds
//   W[kstep*32 + 16*(e>>2) + 4*(l>>4) + (e&3)][nj*16 + (l&15)]
// ---------------------------------------------------------------------------
__global__ void pack_weights(const float* __restrict__ w01, const float* __restrict__ w11,
                             const float* __restrict__ w02, const float* __restrict__ w12,
                             const float* __restrict__ w0o, const float* __restrict__ w1o,
                             const float* __restrict__ tp0, const float* __restrict__ tp1,
                             f16* __restrict__ dst) {
    int u = blockIdx.x * 256 + threadIdx.x;
    if (u >= PACK_UNITS) return;
    const float* src; int NC, base, lu = u;
    if      (lu < 3072) {            src = w01; NC = 192; base = OFF_W01; }
    else if (lu < 3584) { lu -= 3072; src = w11; NC = 64;  base = OFF_W11; }
    else if (lu < 6656) { lu -= 3584; src = w02; NC = 192; base = OFF_W02; }
    else if (lu < 7168) { lu -= 6656; src = w12; NC = 64;  base = OFF_W12; }
    else if (lu < 8192) { lu -= 7168; src = w0o; NC = 64;  base = OFF_W0O; }
    else if (lu < 8704) { lu -= 8192; src = w1o; NC = 64;  base = OFF_W1O; }
    else if (lu < 9216) { lu -= 8704; src = tp0; NC = 64;  base = OFF_TP0; }
    else                { lu -= 9216; src = tp1; NC = 64;  base = OFF_TP1; }
    const int lane = lu & 63;
    const int frag = lu >> 6;          // kstep*NT + nj
    const int NT = NC >> 4;
    const int kstep = frag / NT, nj = frag - kstep * NT;
    const int gl  = lane >> 4;
    const int col = nj * 16 + (lane & 15);
    f16 tmp[8];
    #pragma unroll
    for (int e = 0; e < 8; ++e) {
        const int row = kstep * 32 + ((e >> 2) << 4) + (gl << 2) + (e & 3);  // phi
        tmp[e] = (f16)src[(size_t)row * NC + col];
    }
    *(f16x8*)&dst[(size_t)(base) + (size_t)lu * 8] = *(f16x8*)tmp;
}

// ---------------------------------------------------------------------------
__device__ __forceinline__ int pk2i(float a, float b) {
    union { fp16x2 h; int i; } u;
    u.h = __builtin_amdgcn_cvt_pkrtz(a, b);
    return u.i;
}

// B-fragment from two D-layout f32 tiles (phi-relabeled, pure in-lane).
__device__ __forceinline__ f16x8 packB(f32x4 t0, f32x4 t1) {
    union { i32x4 i; f16x8 v; } u;
    u.i[0] = pk2i(t0[0], t0[1]);
    u.i[1] = pk2i(t0[2], t0[3]);
    u.i[2] = pk2i(t1[0], t1[1]);
    u.i[3] = pk2i(t1[2], t1[3]);
    return u.v;
}

// state fragment: MFMA operand view + packed-half pair view for updates
union Frag { f16x8 v; fp16x2 h2[4]; };

// ---------------------------------------------------------------------------
// One residual block; state in packed f16 B-fragments, 2 sample-halves.
// ---------------------------------------------------------------------------
__device__ __forceinline__ void resblock32(
    Frag (&xsS)[2][4], Frag (&xvS)[2][3][2],
    const f16* __restrict__ w0p, const f16* __restrict__ w1p,
    const float* __restrict__ b0, float invCS, float invCR, int l, int g)
{
    // snapshot xs B-operands (pre-update values for the whole GEMM)
    f16x8 xsB[2][4];
    #pragma unroll
    for (int h = 0; h < 2; ++h)
        #pragma unroll
        for (int ks = 0; ks < 4; ++ks)
            xsB[h][ks] = xsS[h][ks].v;

    float gate[2][4][4];
    // ys^T = W0^T @ xs^T : 12 row-tiles of 16 output features
    #pragma unroll
    for (int nj = 0; nj < 12; ++nj) {
        f32x4 acc0 = {0.f, 0.f, 0.f, 0.f}, acc1 = {0.f, 0.f, 0.f, 0.f};
        #pragma unroll
        for (int ks = 0; ks < 4; ++ks) {
            const f16x8 a = *(const f16x8*)&w0p[(size_t)((ks * 12 + nj) * 64 + l) * 8];
            acc0 = MFMA16(a, xsB[0][ks], acc0);
            acc1 = MFMA16(a, xsB[1][ks], acc1);
        }
        const f32x4 bias = *(const f32x4*)(b0 + nj * 16 + g * 4);
        #pragma unroll
        for (int h = 0; h < 2; ++h) {
            const f32x4 acc = h ? acc1 : acc0;
            if (nj < 8) {
                float s[4];
                #pragma unroll
                for (int r = 0; r < 4; ++r) {
                    const float ys = acc[r] * INV_SQRT_M + bias[r];
                    s[r] = ys / (1.0f + __expf(-ys)) * invCS;
                }
                xsS[h][nj >> 1].h2[2 * (nj & 1)]     += __builtin_amdgcn_cvt_pkrtz(s[0], s[1]);
                xsS[h][nj >> 1].h2[2 * (nj & 1) + 1] += __builtin_amdgcn_cvt_pkrtz(s[2], s[3]);
            } else {
                #pragma unroll
                for (int r = 0; r < 4; ++r) {
                    const float ys = acc[r] * INV_SQRT_M + bias[r];
                    gate[h][nj - 8][r] = fmaxf(ys, 0.f) * invCR;
                }
            }
        }
    }

    // snapshot xv B-operands
    f16x8 xvB[2][3][2];
    #pragma unroll
    for (int h = 0; h < 2; ++h)
        #pragma unroll
        for (int i = 0; i < 3; ++i)
            #pragma unroll
            for (int ks = 0; ks < 2; ++ks)
                xvB[h][i][ks] = xvS[h][i][ks].v;

    // yv^T per i, gated residual update
    #pragma unroll
    for (int i = 0; i < 3; ++i)
        #pragma unroll
        for (int nj = 0; nj < 4; ++nj) {
            f32x4 acc0 = {0.f, 0.f, 0.f, 0.f}, acc1 = {0.f, 0.f, 0.f, 0.f};
            #pragma unroll
            for (int ks = 0; ks < 2; ++ks) {
                const f16x8 a = *(const f16x8*)&w1p[(size_t)((ks * 4 + nj) * 64 + l) * 8];
                acc0 = MFMA16(a, xvB[0][i][ks], acc0);
                acc1 = MFMA16(a, xvB[1][i][ks], acc1);
            }
            #pragma unroll
            for (int h = 0; h < 2; ++h) {
                const f32x4 acc = h ? acc1 : acc0;
                float u[4];
                #pragma unroll
                for (int r = 0; r < 4; ++r)
                    u[r] = acc[r] * INV_SQRT_K * gate[h][nj][r];
                xvS[h][i][nj >> 1].h2[2 * (nj & 1)]     += __builtin_amdgcn_cvt_pkrtz(u[0], u[1]);
                xvS[h][i][nj >> 1].h2[2 * (nj & 1) + 1] += __builtin_amdgcn_cvt_pkrtz(u[2], u[3]);
            }
        }
}

// ---------------------------------------------------------------------------
__global__ __launch_bounds__(256, 2)
void corrnet_reg(const float* __restrict__ x, const float* __restrict__ shift,
                 const float* __restrict__ oscale,
                 const float* __restrict__ b01, const float* __restrict__ b02,
                 const float* __restrict__ b0o,
                 const f16* __restrict__ wp, const float* __restrict__ consts,
                 float* __restrict__ out)
{
    const int t = threadIdx.x;
    const int l = t & 63;
    const int w = __builtin_amdgcn_readfirstlane(t >> 6);
    const int g = l >> 4;
    const int c = l & 15;
    const size_t n0 = (size_t)blockIdx.x * 128 + (size_t)w * 32;

    const float invCS = consts[0], invCR = consts[1];
    const float inv_os = 1.0f / oscale[0];

    // ---- load 2 x-rows per lane -> packed f16 B-fragment state ----
    Frag xsS[2][4];
    Frag xvS[2][3][2];
    #pragma unroll
    for (int h = 0; h < 2; ++h) {
        const float* xrow = x + (n0 + h * 16 + c) * 320;
        #pragma unroll
        for (int ks = 0; ks < 4; ++ks) {
            const int col = ks * 32 + g * 4;
            const f32x4 t0 = *(const f32x4*)(xrow + col)      - *(const f32x4*)(shift + col);
            const f32x4 t1 = *(const f32x4*)(xrow + col + 16) - *(const f32x4*)(shift + col + 16);
            xsS[h][ks].v = packB(t0, t1);
        }
        f32x4 tmp[3][4];
        #pragma unroll
        for (int tau = 0; tau < 4; ++tau) {
            const int col = 128 + 3 * (tau * 16 + g * 4);
            const f32x4 a0 = *(const f32x4*)(xrow + col)     - *(const f32x4*)(shift + col);
            const f32x4 a1 = *(const f32x4*)(xrow + col + 4) - *(const f32x4*)(shift + col + 4);
            const f32x4 a2 = *(const f32x4*)(xrow + col + 8) - *(const f32x4*)(shift + col + 8);
            float arr[12];
            #pragma unroll
            for (int e = 0; e < 4; ++e) {
                arr[e] = a0[e]; arr[4 + e] = a1[e]; arr[8 + e] = a2[e];
            }
            #pragma unroll
            for (int r = 0; r < 4; ++r)
                #pragma unroll
                for (int i = 0; i < 3; ++i)
                    tmp[i][tau][r] = arr[3 * r + i];
        }
        #pragma unroll
        for (int i = 0; i < 3; ++i)
            #pragma unroll
            for (int ks = 0; ks < 2; ++ks)
                xvS[h][i][ks].v = packB(tmp[i][2 * ks], tmp[i][2 * ks + 1]);
    }

    resblock32(xsS, xvS, wp + OFF_W01, wp + OFF_W11, b01, invCS, invCR, l, g);
    resblock32(xsS, xvS, wp + OFF_W02, wp + OFF_W12, b02, invCS, invCR, l, g);

    // ---- output head: zs (reads xs state, no further updates) ----
    f32x4 zs[2][4];
    #pragma unroll
    for (int nj = 0; nj < 4; ++nj) {
        f32x4 acc0 = {0.f, 0.f, 0.f, 0.f}, acc1 = {0.f, 0.f, 0.f, 0.f};
        #pragma unroll
        for (int ks = 0; ks < 4; ++ks) {
            const f16x8 a = *(const f16x8*)&wp[OFF_W0O + (size_t)((ks * 4 + nj) * 64 + l) * 8];
            acc0 = MFMA16(a, xsS[0][ks].v, acc0);
            acc1 = MFMA16(a, xsS[1][ks].v, acc1);
        }
        const f32x4 bias = *(const f32x4*)(b0o + nj * 16 + g * 4);
        #pragma unroll
        for (int h = 0; h < 2; ++h) {
            const f32x4 acc = h ? acc1 : acc0;
            #pragma unroll
            for (int r = 0; r < 4; ++r)
                zs[h][nj][r] = acc[r] * INV_SQRT_M + bias[r];
        }
    }

    float part[2]  = {0.f, 0.f};
    float part1[2] = {0.f, 0.f};

    // ---- y0: zs @ TP0 . zs ----
    {
        f16x8 zsB[2][2];
        #pragma unroll
        for (int h = 0; h < 2; ++h)
            #pragma unroll
            for (int ks = 0; ks < 2; ++ks)
                zsB[h][ks] = packB(zs[h][2 * ks], zs[h][2 * ks + 1]);
        #pragma unroll
        for (int nj = 0; nj < 4; ++nj) {
            f32x4 acc0 = {0.f, 0.f, 0.f, 0.f}, acc1 = {0.f, 0.f, 0.f, 0.f};
            #pragma unroll
            for (int ks = 0; ks < 2; ++ks) {
                const f16x8 a = *(const f16x8*)&wp[OFF_TP0 + (size_t)((ks * 4 + nj) * 64 + l) * 8];
                acc0 = MFMA16(a, zsB[0][ks], acc0);
                acc1 = MFMA16(a, zsB[1][ks], acc1);
            }
            #pragma unroll
            for (int r = 0; r < 4; ++r) {
                part[0] += acc0[r] * zs[0][nj][r];
                part[1] += acc1[r] * zs[1][nj][r];
            }
        }
    }

    // ---- y1: per i, zv = xv_i @ w1o ; zv @ TP1 . zv ----
    #pragma unroll
    for (int i = 0; i < 3; ++i) {
        f32x4 zv[2][4];
        #pragma unroll
        for (int nj = 0; nj < 4; ++nj) {
            f32x4 acc0 = {0.f, 0.f, 0.f, 0.f}, acc1 = {0.f, 0.f, 0.f, 0.f};
            #pragma unroll
            for (int ks = 0; ks < 2; ++ks) {
                const f16x8 a = *(const f16x8*)&wp[OFF_W1O + (size_t)((ks * 4 + nj) * 64 + l) * 8];
                acc0 = MFMA16(a, xvS[0][i][ks].v, acc0);
                acc1 = MFMA16(a, xvS[1][i][ks].v, acc1);
            }
            #pragma unroll
            for (int r = 0; r < 4; ++r) {
                zv[0][nj][r] = acc0[r] * INV_SQRT_K;
                zv[1][nj][r] = acc1[r] * INV_SQRT_K;
            }
        }
        f16x8 zvB[2][2];
        #pragma unroll
        for (int h = 0; h < 2; ++h)
            #pragma unroll
            for (int ks = 0; ks < 2; ++ks)
                zvB[h][ks] = packB(zv[h][2 * ks], zv[h][2 * ks + 1]);
        #pragma unroll
        for (int nj = 0; nj < 4; ++nj) {
            f32x4 acc0 = {0.f, 0.f, 0.f, 0.f}, acc1 = {0.f, 0.f, 0.f, 0.f};
            #pragma unroll
            for (int ks = 0; ks < 2; ++ks) {
                const f16x8 a = *(const f16x8*)&wp[OFF_TP1 + (size_t)((ks * 4 + nj) * 64 + l) * 8];
                acc0 = MFMA16(a, zvB[0][ks], acc0);
                acc1 = MFMA16(a, zvB[1][ks], acc1);
            }
            #pragma unroll
            for (int r = 0; r < 4; ++r) {
                part1[0] += acc0[r] * zv[0][nj][r];
                part1[1] += acc1[r] * zv[1][nj][r];
            }
        }
    }
    #pragma unroll
    for (int h = 0; h < 2; ++h)
        part[h] += part1[h] * INV_SQRT_3;

    // reduce over the 4 g-groups (features) -> per-sample totals
    #pragma unroll
    for (int h = 0; h < 2; ++h) {
        part[h] += __shfl_xor(part[h], 16, 64);
        part[h] += __shfl_xor(part[h], 32, 64);
    }

    if (l < 16)
        out[n0 + l] = part[0] * TP_NORM * inv_os;
    else if (l < 32)
        out[n0 + 16 + (l - 16)] = part[1] * TP_NORM * inv_os;
}

// ---------------------------------------------------------------------------
extern "C" void kernel_launch(void* const* d_in, const int* in_sizes, int n_in,
                              void* d_out, int out_size, void* d_ws, size_t ws_size,
                              hipStream_t stream) {
    const float* x      = (const float*)d_in[0];
    const float* shift  = (const float*)d_in[1];
    const float* oscale = (const float*)d_in[2];
    const float* w01    = (const float*)d_in[3];
    const float* b01    = (const float*)d_in[4];
    const float* w11    = (const float*)d_in[5];
    const float* w02    = (const float*)d_in[6];
    const float* b02    = (const float*)d_in[7];
    const float* w12    = (const float*)d_in[8];
    const float* w0o    = (const float*)d_in[9];
    const float* b0o    = (const float*)d_in[10];
    const float* w1o    = (const float*)d_in[11];
    const float* wtp0   = (const float*)d_in[12];
    const float* wtp1   = (const float*)d_in[13];
    float* out    = (float*)d_out;
    float* consts = (float*)d_ws;
    f16*   wp     = (f16*)((char*)d_ws + 16);

    init_consts_kernel<<<1, 256, 0, stream>>>(consts);
    pack_weights<<<(PACK_UNITS + 255) / 256, 256, 0, stream>>>(
        w01, w11, w02, w12, w0o, w1o, wtp0, wtp1, wp);

    const int nblocks = 131072 / 128;  // 1024
    corrnet_reg<<<nblocks, 256, 0, stream>>>(
        x, shift, oscale, b01, b02, b0o, wp, consts, out);
}